// Round 1
// baseline (284.288 us; speedup 1.0000x reference)
//
#include <hip/hip_runtime.h>
#include <math.h>

#define B_DIM 64
#define C_DIM 768
#define S_DIM 1024   // 32*32 spatial
#define E_DIM 64

// ---------------------------------------------------------------------------
// Kernel 1: global average pool. One 64-lane wave per (b,c) row of 1024 floats.
// Each lane loads 4 float4 (coalesced, 16B/lane), wave shfl reduction.
// ---------------------------------------------------------------------------
__global__ __launch_bounds__(256) void pool_kernel(const float* __restrict__ x,
                                                   float* __restrict__ pooled,
                                                   int nrows) {
    int wave = (int)((blockIdx.x * blockDim.x + threadIdx.x) >> 6);
    int lane = threadIdx.x & 63;
    if (wave >= nrows) return;

    const float4* p = (const float4*)(x + (size_t)wave * S_DIM);
    float s = 0.0f;
#pragma unroll
    for (int k = 0; k < 4; ++k) {
        float4 v = p[k * 64 + lane];
        s += (v.x + v.y) + (v.z + v.w);
    }
#pragma unroll
    for (int off = 1; off < 64; off <<= 1) s += __shfl_xor(s, off);
    if (lane == 0) pooled[wave] = s * (1.0f / (float)S_DIM);
}

// ---------------------------------------------------------------------------
// Kernel 2: per batch row: scores = sigmoid(pooled @ W^T + b); top-K on
// scores + route_bias; gather original scores; normalize; write out.
// Block = 256 threads, grid = B. 4 threads per expert for the 768-dot.
// ---------------------------------------------------------------------------
__global__ __launch_bounds__(256) void gate_kernel(const float* __restrict__ pooled,
                                                   const float* __restrict__ Wm,
                                                   const float* __restrict__ bvec,
                                                   const float* __restrict__ route_bias,
                                                   int K,
                                                   float* __restrict__ out) {
    __shared__ __align__(16) float s_pool[C_DIM];
    __shared__ float s_scores[E_DIM];

    const int b   = blockIdx.x;
    const int tid = threadIdx.x;

    // stage pooled[b,:] into LDS (coalesced)
    const float* prow = pooled + (size_t)b * C_DIM;
    for (int i = tid; i < C_DIM; i += 256) s_pool[i] = prow[i];
    __syncthreads();

    // dot product: expert e handled by 4 consecutive threads (q = chunk)
    const int e = tid >> 2;      // 0..63
    const int q = tid & 3;       // 0..3, each covers 192 channels
    const float4* wrow  = (const float4*)(Wm + (size_t)e * C_DIM + q * 192);
    const float4* prow4 = (const float4*)(s_pool + q * 192);
    float acc = 0.0f;
#pragma unroll 8
    for (int i = 0; i < 48; ++i) {
        float4 wv = wrow[i];
        float4 pv = prow4[i];
        acc += wv.x * pv.x + wv.y * pv.y + wv.z * pv.z + wv.w * pv.w;
    }
    // combine the 4 partials (consecutive lanes in the same wave)
    acc += __shfl_xor(acc, 1);
    acc += __shfl_xor(acc, 2);
    if (q == 0) {
        float z = acc + bvec[e];
        s_scores[e] = 1.0f / (1.0f + expf(-z));
    }
    __syncthreads();

    // top-K selection + normalization by wave 0
    if (tid < 64) {
        const int lane = tid;
        float myval = s_scores[lane] + route_bias[lane];  // biased (selection)
        int sel_idx = 0;
        bool have_sel = false;

        for (int k = 0; k < K; ++k) {
            float v = myval;
            int   i = lane;
#pragma unroll
            for (int off = 1; off < 64; off <<= 1) {
                float ov = __shfl_xor(v, off);
                int   oi = __shfl_xor(i, off);
                // argmax with tie-break to smaller index (lax.top_k semantics)
                if (ov > v || (ov == v && oi < i)) { v = ov; i = oi; }
            }
            if (lane == k) { sel_idx = i; have_sel = true; }
            if (lane == i) myval = -INFINITY;   // remove winner
        }

        float w = have_sel ? s_scores[sel_idx] : 0.0f;  // original score
        float tot = w;
#pragma unroll
        for (int off = 1; off < 64; off <<= 1) tot += __shfl_xor(tot, off);

        if (lane < K) {
            // weights [B,K] then indices [B,K] (as float), flat in d_out
            out[(size_t)b * K + lane] = w / tot;  // ROUTE_SCALE == 1.0
            out[(size_t)B_DIM * K + (size_t)b * K + lane] = (float)sel_idx;
        }
    }
}

extern "C" void kernel_launch(void* const* d_in, const int* in_sizes, int n_in,
                              void* d_out, int out_size, void* d_ws, size_t ws_size,
                              hipStream_t stream) {
    const float* x          = (const float*)d_in[0];
    const float* Wm         = (const float*)d_in[1];
    const float* bvec       = (const float*)d_in[2];
    const float* route_bias = (const float*)d_in[3];
    // d_in[4] is topk (device scalar); K also derivable from out_size:
    const int K = out_size / (2 * B_DIM);   // = 8

    float* pooled = (float*)d_ws;           // B*C floats = 196 KB
    float* out    = (float*)d_out;

    const int nrows  = B_DIM * C_DIM;                 // 49152 waves
    const int blocks = (nrows * 64 + 255) / 256;      // 12288
    pool_kernel<<<blocks, 256, 0, stream>>>(x, pooled, nrows);
    gate_kernel<<<B_DIM, 256, 0, stream>>>(pooled, Wm, bvec, route_bias, K, out);
}